// Round 1
// baseline (8804.410 us; speedup 1.0000x reference)
//
#include <hip/hip_runtime.h>
#include <cstdint>
#include <cstddef>

// Problem constants (match reference)
#define B_  4
#define S_  2048
#define D_  256
#define H_  8
#define FD_ 512              // F*D
#define N_  (B_*S_)          // 8192 rows
#define HD_ (H_*D_)          // 2048 concat dim
#define EPS 1e-5f

// ---------------------------------------------------------------------------
// Kernel A: QKV projections. 24 independent GEMMs (8 heads x {q,k,v}),
// each M=8192, N=256, K=256. Classic 64x64 LDS-tiled fp32 GEMM, 4x4 per
// thread. scale = 256^-0.25 = 0.25 folded into q and k.
// grid (128, 4, 24), block 256.
// ---------------------------------------------------------------------------
__global__ __launch_bounds__(256) void qkv_kernel(
    const float* __restrict__ X, const float* __restrict__ Wq,
    const float* __restrict__ Wk, const float* __restrict__ Wv,
    float* __restrict__ q, float* __restrict__ k, float* __restrict__ v)
{
  __shared__ float As[16][65];   // [k][m], +1 pad
  __shared__ float Bs[16][68];   // [k][n], +4 pad
  const int tid = threadIdx.x;
  const int n0 = blockIdx.x * 64;
  const int e0 = blockIdx.y * 64;
  const int w  = blockIdx.z;

  const float* Wbase;
  float* obase;
  float scale;
  if (w < 8)       { Wbase = Wq + (size_t)w*D_*D_;      obase = q + (size_t)w*N_*D_;      scale = 0.25f; }
  else if (w < 16) { Wbase = Wk + (size_t)(w-8)*D_*D_;  obase = k + (size_t)(w-8)*N_*D_;  scale = 0.25f; }
  else             { Wbase = Wv + (size_t)(w-16)*D_*D_; obase = v + (size_t)(w-16)*N_*D_; scale = 1.0f;  }

  float acc[4][4] = {};
  const int ty = tid / 16, tx = tid % 16;

  for (int k0 = 0; k0 < D_; k0 += 16) {
    {
      // A tile: X[n0..+64][k0..+16] -> As transposed
      int row = tid / 4, c4 = (tid % 4) * 4;
      float4 a = *(const float4*)&X[(size_t)(n0+row)*D_ + k0 + c4];
      As[c4+0][row] = a.x; As[c4+1][row] = a.y; As[c4+2][row] = a.z; As[c4+3][row] = a.w;
      // B tile: W[k0..+16][e0..+64]
      int rw = tid / 16, cc = (tid % 16) * 4;
      *(float4*)&Bs[rw][cc] = *(const float4*)&Wbase[(size_t)(k0+rw)*D_ + e0 + cc];
    }
    __syncthreads();
    #pragma unroll
    for (int kk = 0; kk < 16; ++kk) {
      float4 a4 = *(const float4*)&As[kk][ty*4];
      float4 b4 = *(const float4*)&Bs[kk][tx*4];
      float av[4] = {a4.x, a4.y, a4.z, a4.w};
      float bv[4] = {b4.x, b4.y, b4.z, b4.w};
      #pragma unroll
      for (int i = 0; i < 4; ++i)
        #pragma unroll
        for (int j = 0; j < 4; ++j) acc[i][j] += av[i] * bv[j];
    }
    __syncthreads();
  }

  #pragma unroll
  for (int i = 0; i < 4; ++i) {
    int n = n0 + ty*4 + i;
    float4 o = make_float4(acc[i][0]*scale, acc[i][1]*scale, acc[i][2]*scale, acc[i][3]*scale);
    *(float4*)&obase[(size_t)n*D_ + e0 + tx*4] = o;
  }
}

// ---------------------------------------------------------------------------
// Kernel B: attention. One block per (h, b, 16-row q tile). Exact softmax:
// the full 16x2048 score tile lives in LDS (gfx950 LDS = 160 KB/CU; we use
// ~150 KB -> 1 block/CU). Phases:
//   1. scores  S = q_tile . K^T    (K streamed from global/L2)
//   2. row max / exp / row sum     (stored p stays UNNORMALIZED in LDS)
//   3. attn_mean += p * invl / 8   (atomicAdd; only H=8-way contention)
//   4. zh = p @ V, scaled by invl at the end; written into zcat layout
// grid (128, 4, 8), block 256.
// ---------------------------------------------------------------------------
__global__ __launch_bounds__(256) void attn_kernel(
    const float* __restrict__ q, const float* __restrict__ k,
    const float* __restrict__ v, float* __restrict__ zcat,
    float* __restrict__ attn_out)
{
  __shared__ float qs[16][260];    // q tile, padded (16.6 KB)
  __shared__ float sc[16][2052];   // score/p tile, padded (131.3 KB)
  __shared__ float red[2][16][16]; // row-reduction partials
  __shared__ float invl[16];

  const int tid = threadIdx.x;
  const int s0 = blockIdx.x * 16;
  const int b  = blockIdx.y;
  const int h  = blockIdx.z;
  const float* qh = q + (size_t)h*N_*D_ + (size_t)(b*S_ + s0)*D_;
  const float* kh = k + (size_t)h*N_*D_ + (size_t)b*S_*D_;
  const float* vh = v + (size_t)h*N_*D_ + (size_t)b*S_*D_;

  { // load q tile (coalesced)
    int row = tid / 16, c = (tid % 16) * 16;
    #pragma unroll
    for (int u = 0; u < 4; ++u)
      *(float4*)&qs[row][c + u*4] = *(const float4*)&qh[(size_t)row*D_ + c + u*4];
  }
  __syncthreads();

  { // phase 1: scores. thread (sx, tw) computes rows sx, t = tt*128+tw*8+j.
    // 16 lanes share each k-row address (HW broadcast); q reused across 8 t.
    const int sx = tid % 16, tw = tid / 16;
    for (int tt = 0; tt < 16; ++tt) {
      const int tb = tt*128 + tw*8;
      float acc8[8] = {};
      for (int d0 = 0; d0 < D_; d0 += 32) {
        float4 qv[8];
        #pragma unroll
        for (int u = 0; u < 8; ++u) qv[u] = *(const float4*)&qs[sx][d0 + u*4];
        #pragma unroll
        for (int j = 0; j < 8; ++j) {
          const float* kr = kh + (size_t)(tb+j)*D_ + d0;
          #pragma unroll
          for (int u = 0; u < 8; ++u) {
            float4 kv = *(const float4*)(kr + u*4);
            acc8[j] += qv[u].x*kv.x + qv[u].y*kv.y + qv[u].z*kv.z + qv[u].w*kv.w;
          }
        }
      }
      #pragma unroll
      for (int j = 0; j < 8; ++j) sc[sx][tb+j] = acc8[j];
    }
  }
  __syncthreads();

  // phase 2: softmax stats. thread (r = tid%16, c = tid/16) scans 128 cols.
  const int r = tid % 16, c = tid / 16;
  {
    float m = -1e30f;
    for (int i = c*128; i < c*128 + 128; ++i) m = fmaxf(m, sc[r][i]);
    red[0][r][c] = m;
  }
  __syncthreads();
  float mrow = -1e30f;
  #pragma unroll
  for (int j = 0; j < 16; ++j) mrow = fmaxf(mrow, red[0][r][j]);
  {
    float s = 0.f;
    for (int i = c*128; i < c*128 + 128; ++i) {
      float e = __expf(sc[r][i] - mrow);
      sc[r][i] = e;              // keep UNNORMALIZED
      s += e;
    }
    red[1][r][c] = s;
  }
  __syncthreads();
  if (tid < 16) {
    float l = 0.f;
    #pragma unroll
    for (int j = 0; j < 16; ++j) l += red[1][tid][j];
    invl[tid] = 1.0f / l;
  }
  __syncthreads();

  { // phase 3: attn_mean accumulation (coalesced atomics, rows contiguous)
    float* ab = attn_out + (size_t)(b*S_ + s0) * S_;
    for (int it = 0; it < 128; ++it) {
      int idx = it*256 + tid;
      int rr = idx >> 11;        // /2048
      int t  = idx & 2047;
      atomicAdd(&ab[(size_t)rr*S_ + t], 0.125f * invl[rr] * sc[rr][t]);
    }
  }

  { // phase 4: zh = p @ V. wave w owns e-slice [w*64, w*64+64): V read once
    // per block. lane -> (sg = lane/16 row subgroup, le*4 e offset).
    const int wave = tid / 64, lane = tid % 64;
    const int sg = lane / 16, le = lane % 16;
    const int e0 = wave*64 + le*4;
    float acc[4][4] = {};
    #pragma unroll 4
    for (int t = 0; t < S_; ++t) {
      float4 vv = *(const float4*)&vh[(size_t)t*D_ + e0];
      #pragma unroll
      for (int i = 0; i < 4; ++i) {
        float p = sc[sg + 4*i][t];
        acc[i][0] += p*vv.x; acc[i][1] += p*vv.y;
        acc[i][2] += p*vv.z; acc[i][3] += p*vv.w;
      }
    }
    #pragma unroll
    for (int i = 0; i < 4; ++i) {
      int s = sg + 4*i;
      float il = invl[s];
      float4 o = make_float4(acc[i][0]*il, acc[i][1]*il, acc[i][2]*il, acc[i][3]*il);
      *(float4*)&zcat[(size_t)(b*S_ + s0 + s)*HD_ + h*D_ + e0] = o;
    }
  }
}

// ---------------------------------------------------------------------------
// Kernel C: z = zcat @ Wz + bz; r = z + X; z1 = LN1(r).
// Row-complete tile: 32 rows x all 256 cols per block so LN fuses in-block.
// K = 2048, BK = 32. grid 256, block 256 (8 row-groups x 32 col-threads).
// ---------------------------------------------------------------------------
__global__ __launch_bounds__(256) void wz_ln1_kernel(
    const float* __restrict__ zcat, const float* __restrict__ Wz,
    const float* __restrict__ bz, const float* __restrict__ X,
    const float* __restrict__ g1, const float* __restrict__ be1,
    float* __restrict__ z1)
{
  __shared__ float As[32][33];    // [k][m]
  __shared__ float Bs[32][258];   // [k][n]
  const int tid = threadIdx.x;
  const int n0 = blockIdx.x * 32;
  const int ty = tid / 32, tx = tid % 32;   // rows ty*4..+4, cols tx*4 & tx*4+128

  float acc[4][8] = {};
  for (int k0 = 0; k0 < HD_; k0 += 32) {
    {
      int row = tid / 8, c4 = (tid % 8) * 4;
      float4 a = *(const float4*)&zcat[(size_t)(n0+row)*HD_ + k0 + c4];
      As[c4+0][row] = a.x; As[c4+1][row] = a.y; As[c4+2][row] = a.z; As[c4+3][row] = a.w;
      #pragma unroll
      for (int u = 0; u < 8; ++u) {
        int f4 = tid + u*256;               // 2048 float4s = 32x256 tile
        int rw = f4 / 64, cc = (f4 % 64) * 4;
        *(float4*)&Bs[rw][cc] = *(const float4*)&Wz[(size_t)(k0+rw)*D_ + cc];
      }
    }
    __syncthreads();
    #pragma unroll
    for (int kk = 0; kk < 32; ++kk) {
      float4 a4 = *(const float4*)&As[kk][ty*4];
      float4 b0 = *(const float4*)&Bs[kk][tx*4];
      float4 b1v = *(const float4*)&Bs[kk][tx*4 + 128];
      float av[4] = {a4.x, a4.y, a4.z, a4.w};
      float bv[8] = {b0.x, b0.y, b0.z, b0.w, b1v.x, b1v.y, b1v.z, b1v.w};
      #pragma unroll
      for (int i = 0; i < 4; ++i)
        #pragma unroll
        for (int j = 0; j < 8; ++j) acc[i][j] += av[i] * bv[j];
    }
    __syncthreads();
  }

  // epilogue: bias + residual + LN1 (row-mates are 32 consecutive lanes)
  float vals[4][8], psum[4], psq[4];
  #pragma unroll
  for (int i = 0; i < 4; ++i) {
    int n = n0 + ty*4 + i;
    psum[i] = 0.f; psq[i] = 0.f;
    #pragma unroll
    for (int j = 0; j < 8; ++j) {
      int cidx = (j < 4) ? tx*4 + j : tx*4 + 128 + (j - 4);
      float val = acc[i][j] + bz[cidx] + X[(size_t)n*D_ + cidx];
      vals[i][j] = val;
      psum[i] += val; psq[i] += val*val;
    }
  }
  #pragma unroll
  for (int off = 16; off; off >>= 1) {
    #pragma unroll
    for (int i = 0; i < 4; ++i) {
      psum[i] += __shfl_xor(psum[i], off, 32);
      psq[i]  += __shfl_xor(psq[i],  off, 32);
    }
  }
  #pragma unroll
  for (int i = 0; i < 4; ++i) {
    int n = n0 + ty*4 + i;
    float mean = psum[i] * (1.0f/D_);
    float var  = psq[i] * (1.0f/D_) - mean*mean;
    float rstd = rsqrtf(var + EPS);
    #pragma unroll
    for (int j = 0; j < 8; ++j) {
      int cidx = (j < 4) ? tx*4 + j : tx*4 + 128 + (j - 4);
      z1[(size_t)n*D_ + cidx] = (vals[i][j] - mean)*rstd*g1[cidx] + be1[cidx];
    }
  }
}

// ---------------------------------------------------------------------------
// Kernel D: z_ff = relu(z1@W1 + b1)@W2 + b2; out = LN2(z_ff + z1).
// 4 rows per block; W1/W2 streamed coalesced (f = tid contiguous), z1/hid
// broadcast from LDS. grid 2048, block 256.
// ---------------------------------------------------------------------------
__global__ __launch_bounds__(256) void mlp_ln2_kernel(
    const float* __restrict__ z1, const float* __restrict__ W1,
    const float* __restrict__ b1, const float* __restrict__ W2,
    const float* __restrict__ b2, const float* __restrict__ g2,
    const float* __restrict__ be2, float* __restrict__ out)
{
  __shared__ float zs[4][D_];
  __shared__ float hs[4][FD_];
  __shared__ float red[4][4][2];
  const int tid = threadIdx.x;
  const int n0 = blockIdx.x * 4;

  {
    int row = tid / 64, c4 = (tid % 64) * 4;
    *(float4*)&zs[row][c4] = *(const float4*)&z1[(size_t)(n0+row)*D_ + c4];
  }
  __syncthreads();

  { // hidden layer: thread owns f = tid and tid+256
    float acc0[4], acc1[4];
    #pragma unroll
    for (int r2 = 0; r2 < 4; ++r2) { acc0[r2] = b1[tid]; acc1[r2] = b1[tid+256]; }
    #pragma unroll 4
    for (int d = 0; d < D_; ++d) {
      float w0 = W1[(size_t)d*FD_ + tid];
      float w1 = W1[(size_t)d*FD_ + tid + 256];
      #pragma unroll
      for (int r2 = 0; r2 < 4; ++r2) {
        float zr = zs[r2][d];
        acc0[r2] += zr*w0; acc1[r2] += zr*w1;
      }
    }
    #pragma unroll
    for (int r2 = 0; r2 < 4; ++r2) {
      hs[r2][tid]     = fmaxf(acc0[r2], 0.f);
      hs[r2][tid+256] = fmaxf(acc1[r2], 0.f);
    }
  }
  __syncthreads();

  { // output layer + residual + LN2; thread owns column c = tid
    const int cidx = tid;
    float o[4];
    #pragma unroll
    for (int r2 = 0; r2 < 4; ++r2) o[r2] = b2[cidx];
    #pragma unroll 4
    for (int f = 0; f < FD_; ++f) {
      float w2 = W2[(size_t)f*D_ + cidx];
      #pragma unroll
      for (int r2 = 0; r2 < 4; ++r2) o[r2] += hs[r2][f]*w2;
    }
    float psum[4], psq[4];
    #pragma unroll
    for (int r2 = 0; r2 < 4; ++r2) {
      o[r2] += zs[r2][cidx];
      psum[r2] = o[r2]; psq[r2] = o[r2]*o[r2];
    }
    #pragma unroll
    for (int off = 32; off; off >>= 1) {
      #pragma unroll
      for (int r2 = 0; r2 < 4; ++r2) {
        psum[r2] += __shfl_xor(psum[r2], off, 64);
        psq[r2]  += __shfl_xor(psq[r2],  off, 64);
      }
    }
    const int wave = tid / 64;
    if ((tid % 64) == 0) {
      #pragma unroll
      for (int r2 = 0; r2 < 4; ++r2) { red[wave][r2][0] = psum[r2]; red[wave][r2][1] = psq[r2]; }
    }
    __syncthreads();
    #pragma unroll
    for (int r2 = 0; r2 < 4; ++r2) {
      float s  = red[0][r2][0] + red[1][r2][0] + red[2][r2][0] + red[3][r2][0];
      float sq = red[0][r2][1] + red[1][r2][1] + red[2][r2][1] + red[3][r2][1];
      float mean = s * (1.0f/D_);
      float var  = sq * (1.0f/D_) - mean*mean;
      float rstd = rsqrtf(var + EPS);
      out[(size_t)(n0+r2)*D_ + cidx] = (o[r2] - mean)*rstd*g2[cidx] + be2[cidx];
    }
  }
}

// ---------------------------------------------------------------------------
// ws layout (floats): q[H*N*D] | k[H*N*D] | v[H*N*D] | zcat[N*HD] | z1[N*D]
// total = 69,206,016 floats = 277 MB.
// d_out: z [N*D] then attn_mean [B*S*S] (tuple order).
// ---------------------------------------------------------------------------
extern "C" void kernel_launch(void* const* d_in, const int* in_sizes, int n_in,
                              void* d_out, int out_size, void* d_ws, size_t ws_size,
                              hipStream_t stream)
{
  (void)in_sizes; (void)n_in; (void)out_size; (void)ws_size;
  const float* X   = (const float*)d_in[0];
  const float* Wq  = (const float*)d_in[1];
  const float* Wk  = (const float*)d_in[2];
  const float* Wv  = (const float*)d_in[3];
  const float* Wz  = (const float*)d_in[4];
  const float* bz  = (const float*)d_in[5];
  const float* W1  = (const float*)d_in[6];
  const float* b1  = (const float*)d_in[7];
  const float* W2  = (const float*)d_in[8];
  const float* b2  = (const float*)d_in[9];
  const float* g1  = (const float*)d_in[10];
  const float* be1 = (const float*)d_in[11];
  const float* g2  = (const float*)d_in[12];
  const float* be2 = (const float*)d_in[13];

  float* ws   = (float*)d_ws;
  float* q    = ws;
  float* kbuf = q    + (size_t)H_*N_*D_;
  float* vbuf = kbuf + (size_t)H_*N_*D_;
  float* zcat = vbuf + (size_t)H_*N_*D_;
  float* z1   = zcat + (size_t)N_*HD_;

  float* out_z    = (float*)d_out;
  float* out_attn = out_z + (size_t)N_*D_;

  // attn_mean is accumulated with atomics -> must start at zero every call
  hipMemsetAsync(out_attn, 0, (size_t)B_*S_*S_*sizeof(float), stream);

  dim3 gA(N_/64, D_/64, 24);
  qkv_kernel<<<gA, 256, 0, stream>>>(X, Wq, Wk, Wv, q, kbuf, vbuf);

  dim3 gAt(S_/16, B_, H_);
  attn_kernel<<<gAt, 256, 0, stream>>>(q, kbuf, vbuf, zcat, out_attn);

  wz_ln1_kernel<<<N_/32, 256, 0, stream>>>(zcat, Wz, bz, X, g1, be1, z1);

  mlp_ln2_kernel<<<N_/4, 256, 0, stream>>>(z1, W1, b1, W2, b2, g2, be2, out_z);
}